// Round 1
// baseline (438.027 us; speedup 1.0000x reference)
//
#include <hip/hip_runtime.h>

#define NB 4
#define NH 16
#define SS 2048
#define DD 64
#define NEG -1000000000.0f

#define QT 64      // query rows per block (16 per wave)
#define KT 64      // keys per tile
#define DP 72      // padded LDS stride (bf16 elems): 144B rows -> 16B aligned, banks spread

typedef __bf16 bf16x8 __attribute__((ext_vector_type(8)));
typedef __bf16 bf16x2 __attribute__((ext_vector_type(2)));
typedef float  floatx4 __attribute__((ext_vector_type(4)));

static_assert(sizeof(bf16x8) == 16, "bf16x8 must be 16B");

__global__ __launch_bounds__(256)
void attn_kernel(const float* __restrict__ Q, const float* __restrict__ K,
                 const float* __restrict__ V, const int* __restrict__ M,
                 float* __restrict__ O)
{
    __shared__ __bf16 ks[KT][DP];        // K tile, [key][dim]
    __shared__ __bf16 vsT[DD][DP];       // V tile transposed, [dim][key]
    __shared__ __bf16 ps[4][16][DP];     // per-wave P tile, [qrow][key]

    const int t    = threadIdx.x;
    const int wave = t >> 6;
    const int lane = t & 63;
    const int l15  = lane & 15;
    const int quad = lane >> 4;

    const int bh    = blockIdx.x >> 5;   // 32 q-tiles per (b,h)
    const int qtile = blockIdx.x & 31;
    const int b     = bh >> 4;
    const int q0    = qtile * QT + wave * 16;

    const size_t base = (size_t)bh * SS * DD;
    const float* Qb = Q + base;
    const float* Kb = K + base;
    const float* Vb = V + base;
    const int*   Mb = M + (size_t)b * SS * SS;

    // ---- persistent Q A-fragments (scaled by 1/temperature) ----
    bf16x8 aq[2];
    {
        const float* qp = Qb + (size_t)(q0 + l15) * DD + quad * 8;
        #pragma unroll
        for (int kc = 0; kc < 2; ++kc) {
            float4 f0 = *(const float4*)(qp + kc * 32);
            float4 f1 = *(const float4*)(qp + kc * 32 + 4);
            bf16x8 a;
            a[0] = (__bf16)(f0.x * 0.125f); a[1] = (__bf16)(f0.y * 0.125f);
            a[2] = (__bf16)(f0.z * 0.125f); a[3] = (__bf16)(f0.w * 0.125f);
            a[4] = (__bf16)(f1.x * 0.125f); a[5] = (__bf16)(f1.y * 0.125f);
            a[6] = (__bf16)(f1.z * 0.125f); a[7] = (__bf16)(f1.w * 0.125f);
            aq[kc] = a;
        }
    }

    // staging assignments
    const int skey = t >> 2;            // K: key 0..63
    const int sdc  = (t & 3) * 16;      // K: 16 dims
    const int vkp  = t & 31;            // V: key pair (2*vkp, 2*vkp+1)
    const int vdc  = (t >> 5) * 8;      // V: 8 dims

    floatx4 o[4];
    #pragma unroll
    for (int nt = 0; nt < 4; ++nt) { o[nt][0]=0.f; o[nt][1]=0.f; o[nt][2]=0.f; o[nt][3]=0.f; }
    float mr[4] = {-3.0e38f, -3.0e38f, -3.0e38f, -3.0e38f};
    float lr[4] = {0.f, 0.f, 0.f, 0.f};

    for (int j0 = 0; j0 < SS; j0 += KT) {
        __syncthreads();   // previous tile's LDS consumers done

        // ---- stage K tile (bf16, natural layout) ----
        {
            const float* kp_ = Kb + (size_t)(j0 + skey) * DD + sdc;
            float4 f0 = ((const float4*)kp_)[0];
            float4 f1 = ((const float4*)kp_)[1];
            float4 f2 = ((const float4*)kp_)[2];
            float4 f3 = ((const float4*)kp_)[3];
            bf16x8 w0, w1;
            w0[0]=(__bf16)f0.x; w0[1]=(__bf16)f0.y; w0[2]=(__bf16)f0.z; w0[3]=(__bf16)f0.w;
            w0[4]=(__bf16)f1.x; w0[5]=(__bf16)f1.y; w0[6]=(__bf16)f1.z; w0[7]=(__bf16)f1.w;
            w1[0]=(__bf16)f2.x; w1[1]=(__bf16)f2.y; w1[2]=(__bf16)f2.z; w1[3]=(__bf16)f2.w;
            w1[4]=(__bf16)f3.x; w1[5]=(__bf16)f3.y; w1[6]=(__bf16)f3.z; w1[7]=(__bf16)f3.w;
            *(bf16x8*)&ks[skey][sdc]     = w0;
            *(bf16x8*)&ks[skey][sdc + 8] = w1;
        }
        // ---- stage V tile transposed: vsT[dim][key], paired b32 writes ----
        {
            const float* va  = Vb + (size_t)(j0 + 2 * vkp) * DD + vdc;
            const float* vb2 = va + DD;
            float4 a0 = ((const float4*)va)[0],  a1 = ((const float4*)va)[1];
            float4 b0 = ((const float4*)vb2)[0], b1 = ((const float4*)vb2)[1];
            float av[8] = {a0.x,a0.y,a0.z,a0.w,a1.x,a1.y,a1.z,a1.w};
            float bv[8] = {b0.x,b0.y,b0.z,b0.w,b1.x,b1.y,b1.z,b1.w};
            #pragma unroll
            for (int i = 0; i < 8; ++i) {
                bf16x2 pr; pr[0] = (__bf16)av[i]; pr[1] = (__bf16)bv[i];
                *(bf16x2*)&vsT[vdc + i][2 * vkp] = pr;
            }
        }
        __syncthreads();   // staged tile visible

        // ---- QK^T: 16x64 scores per wave ----
        floatx4 c[4];
        #pragma unroll
        for (int nt = 0; nt < 4; ++nt) {
            bf16x8 b0 = *(const bf16x8*)&ks[nt * 16 + l15][quad * 8];
            bf16x8 b1 = *(const bf16x8*)&ks[nt * 16 + l15][32 + quad * 8];
            floatx4 z; z[0]=0.f; z[1]=0.f; z[2]=0.f; z[3]=0.f;
            z = __builtin_amdgcn_mfma_f32_16x16x32_bf16(aq[0], b0, z, 0, 0, 0);
            z = __builtin_amdgcn_mfma_f32_16x16x32_bf16(aq[1], b1, z, 0, 0, 0);
            c[nt] = z;
        }

        // ---- mask (C-layout: col = key = nt*16+l15, row = quad*4+r) ----
        {
            const int* mrow = Mb + (size_t)(q0 + quad * 4) * SS + j0 + l15;
            #pragma unroll
            for (int r = 0; r < 4; ++r) {
                const int* mrp = mrow + (size_t)r * SS;
                #pragma unroll
                for (int nt = 0; nt < 4; ++nt) {
                    if (mrp[nt * 16] == 1) c[nt][r] = NEG;
                }
            }
        }

        // ---- online softmax per row ----
        #pragma unroll
        for (int r = 0; r < 4; ++r) {
            float rm = fmaxf(fmaxf(c[0][r], c[1][r]), fmaxf(c[2][r], c[3][r]));
            rm = fmaxf(rm, __shfl_xor(rm, 1));
            rm = fmaxf(rm, __shfl_xor(rm, 2));
            rm = fmaxf(rm, __shfl_xor(rm, 4));
            rm = fmaxf(rm, __shfl_xor(rm, 8));
            float mnew  = fmaxf(mr[r], rm);
            float alpha = __expf(mr[r] - mnew);
            mr[r] = mnew;
            float psum = 0.f;
            #pragma unroll
            for (int nt = 0; nt < 4; ++nt) {
                float p = __expf(c[nt][r] - mnew);
                c[nt][r] = p;
                psum += p;
            }
            psum += __shfl_xor(psum, 1);
            psum += __shfl_xor(psum, 2);
            psum += __shfl_xor(psum, 4);
            psum += __shfl_xor(psum, 8);
            lr[r] = lr[r] * alpha + psum;
            #pragma unroll
            for (int nt = 0; nt < 4; ++nt) o[nt][r] *= alpha;
        }

        // ---- P (C-layout) -> LDS [qrow][key] for A-layout reload ----
        #pragma unroll
        for (int r = 0; r < 4; ++r) {
            #pragma unroll
            for (int nt = 0; nt < 4; ++nt) {
                ps[wave][quad * 4 + r][nt * 16 + l15] = (__bf16)c[nt][r];
            }
        }
        // same-wave DS ordering guarantees write->read consistency
        bf16x8 ap0 = *(const bf16x8*)&ps[wave][l15][quad * 8];
        bf16x8 ap1 = *(const bf16x8*)&ps[wave][l15][32 + quad * 8];

        // ---- PV: O[16x64] += P[16x64] * V[64x64] ----
        #pragma unroll
        for (int nt = 0; nt < 4; ++nt) {
            bf16x8 bv0 = *(const bf16x8*)&vsT[nt * 16 + l15][quad * 8];
            bf16x8 bv1 = *(const bf16x8*)&vsT[nt * 16 + l15][32 + quad * 8];
            o[nt] = __builtin_amdgcn_mfma_f32_16x16x32_bf16(ap0, bv0, o[nt], 0, 0, 0);
            o[nt] = __builtin_amdgcn_mfma_f32_16x16x32_bf16(ap1, bv1, o[nt], 0, 0, 0);
        }
    }

    // ---- epilogue: divide by l, store fp32 ----
    #pragma unroll
    for (int r = 0; r < 4; ++r) {
        float inv = 1.0f / lr[r];
        float* op = O + base + (size_t)(q0 + quad * 4 + r) * DD + l15;
        #pragma unroll
        for (int nt = 0; nt < 4; ++nt) op[nt * 16] = o[nt][r] * inv;
    }
}

extern "C" void kernel_launch(void* const* d_in, const int* in_sizes, int n_in,
                              void* d_out, int out_size, void* d_ws, size_t ws_size,
                              hipStream_t stream) {
    (void)in_sizes; (void)n_in; (void)out_size; (void)d_ws; (void)ws_size;
    const float* q = (const float*)d_in[0];
    const float* k = (const float*)d_in[1];
    const float* v = (const float*)d_in[2];
    const int*   m = (const int*)d_in[3];
    float* out = (float*)d_out;
    dim3 grid(NB * NH * (SS / QT));   // 2048 blocks
    attn_kernel<<<grid, 256, 0, stream>>>(q, k, v, m, out);
}

// Round 2
// 408.637 us; speedup vs baseline: 1.0719x; 1.0719x over previous
//
#include <hip/hip_runtime.h>

#define NB 4
#define NH 16
#define SS 2048
#define DD 64
#define QT 64      // query rows per block (16 per wave)
#define KT 64      // keys per tile
#define DP 72      // padded LDS stride (bf16 elems)
#define QSCALE 0.18033688011112042f   // (1/8) * log2(e)  -> exp2 domain

typedef __bf16 bf16x8 __attribute__((ext_vector_type(8)));
typedef __bf16 bf16x2 __attribute__((ext_vector_type(2)));
typedef float  floatx4 __attribute__((ext_vector_type(4)));

static_assert(sizeof(bf16x8) == 16, "bf16x8 must be 16B");

__global__ __launch_bounds__(256, 4)
void attn_kernel(const float* __restrict__ Q, const float* __restrict__ K,
                 const float* __restrict__ V, const int* __restrict__ M,
                 float* __restrict__ O)
{
    __shared__ __bf16 ks[KT][DP];        // K tile, [key][dim]
    __shared__ __bf16 vsT[DD][DP];       // V tile transposed, [dim][key]
    __shared__ __bf16 ps[4][16][DP];     // per-wave P tile, [qrow][key]

    const int t    = threadIdx.x;
    const int wave = t >> 6;
    const int lane = t & 63;
    const int l15  = lane & 15;
    const int quad = lane >> 4;

    const int bh    = blockIdx.x >> 5;
    const int qtile = blockIdx.x & 31;
    const int b     = bh >> 4;
    const int q0    = qtile * QT + wave * 16;

    const size_t base = (size_t)bh * SS * DD;
    const float* Qb = Q + base;
    const float* Kb = K + base;
    const float* Vb = V + base;
    const int*   Mb = M + (size_t)b * SS * SS;

    // ---- persistent Q A-fragments, scaled into exp2 domain ----
    bf16x8 aq[2];
    {
        const float* qp = Qb + (size_t)(q0 + l15) * DD + quad * 8;
        #pragma unroll
        for (int kc = 0; kc < 2; ++kc) {
            float4 f0 = *(const float4*)(qp + kc * 32);
            float4 f1 = *(const float4*)(qp + kc * 32 + 4);
            bf16x8 a;
            a[0] = (__bf16)(f0.x * QSCALE); a[1] = (__bf16)(f0.y * QSCALE);
            a[2] = (__bf16)(f0.z * QSCALE); a[3] = (__bf16)(f0.w * QSCALE);
            a[4] = (__bf16)(f1.x * QSCALE); a[5] = (__bf16)(f1.y * QSCALE);
            a[6] = (__bf16)(f1.z * QSCALE); a[7] = (__bf16)(f1.w * QSCALE);
            aq[kc] = a;
        }
    }

    // staging assignments
    const int skey = t >> 2;            // K: key 0..63
    const int sdc  = (t & 3) * 16;      // K: 16 dims
    const int vkp  = t & 31;            // V: key pair
    const int vdc  = (t >> 5) * 8;      // V: 8 dims

    const float* kpre = Kb + (size_t)skey * DD + sdc;
    const float* vpre = Vb + (size_t)(2 * vkp) * DD + vdc;

    // ---- prologue: prefetch tile 0 into registers ----
    float4 kr0, kr1, kr2, kr3, vr0, vr1, vr2, vr3;
    kr0 = ((const float4*)kpre)[0]; kr1 = ((const float4*)kpre)[1];
    kr2 = ((const float4*)kpre)[2]; kr3 = ((const float4*)kpre)[3];
    vr0 = ((const float4*)vpre)[0]; vr1 = ((const float4*)vpre)[1];
    vr2 = ((const float4*)(vpre + DD))[0]; vr3 = ((const float4*)(vpre + DD))[1];

    const int* mp[4];
    #pragma unroll
    for (int r = 0; r < 4; ++r)
        mp[r] = Mb + (size_t)(q0 + quad * 4 + r) * SS + l15;

    floatx4 o[4];
    floatx4 ol;
    #pragma unroll
    for (int nt = 0; nt < 4; ++nt) { o[nt][0]=0.f; o[nt][1]=0.f; o[nt][2]=0.f; o[nt][3]=0.f; }
    ol[0]=0.f; ol[1]=0.f; ol[2]=0.f; ol[3]=0.f;
    float mr[4] = {-3.0e38f, -3.0e38f, -3.0e38f, -3.0e38f};

    bf16x8 ones;
    #pragma unroll
    for (int i = 0; i < 8; ++i) ones[i] = (__bf16)1.0f;

    for (int j0 = 0; j0 < SS; j0 += KT) {
        __syncthreads();   // previous tile's LDS consumers done

        // ---- write prefetched K regs -> LDS ----
        {
            bf16x8 w0, w1;
            w0[0]=(__bf16)kr0.x; w0[1]=(__bf16)kr0.y; w0[2]=(__bf16)kr0.z; w0[3]=(__bf16)kr0.w;
            w0[4]=(__bf16)kr1.x; w0[5]=(__bf16)kr1.y; w0[6]=(__bf16)kr1.z; w0[7]=(__bf16)kr1.w;
            w1[0]=(__bf16)kr2.x; w1[1]=(__bf16)kr2.y; w1[2]=(__bf16)kr2.z; w1[3]=(__bf16)kr2.w;
            w1[4]=(__bf16)kr3.x; w1[5]=(__bf16)kr3.y; w1[6]=(__bf16)kr3.z; w1[7]=(__bf16)kr3.w;
            *(bf16x8*)&ks[skey][sdc]     = w0;
            *(bf16x8*)&ks[skey][sdc + 8] = w1;
        }
        // ---- write prefetched V regs -> LDS transposed ----
        {
            float av[8] = {vr0.x,vr0.y,vr0.z,vr0.w,vr1.x,vr1.y,vr1.z,vr1.w};
            float bv[8] = {vr2.x,vr2.y,vr2.z,vr2.w,vr3.x,vr3.y,vr3.z,vr3.w};
            #pragma unroll
            for (int i = 0; i < 8; ++i) {
                bf16x2 pr; pr[0] = (__bf16)av[i]; pr[1] = (__bf16)bv[i];
                *(bf16x2*)&vsT[vdc + i][2 * vkp] = pr;
            }
        }
        __syncthreads();   // staged tile visible

        // ---- issue mask loads for CURRENT tile (consumed post-exp) ----
        int mk[4][4];
        #pragma unroll
        for (int r = 0; r < 4; ++r) {
            #pragma unroll
            for (int nt = 0; nt < 4; ++nt) mk[r][nt] = mp[r][nt * 16];
            mp[r] += KT;
        }

        // ---- issue K/V prefetch for NEXT tile ----
        {
            int jn = (j0 + KT) & (SS - 1);           // wraps on last iter (unused)
            const float* kn = kpre + (size_t)jn * DD;
            kr0 = ((const float4*)kn)[0]; kr1 = ((const float4*)kn)[1];
            kr2 = ((const float4*)kn)[2]; kr3 = ((const float4*)kn)[3];
            const float* vn = vpre + (size_t)jn * DD;
            vr0 = ((const float4*)vn)[0]; vr1 = ((const float4*)vn)[1];
            vr2 = ((const float4*)(vn + DD))[0]; vr3 = ((const float4*)(vn + DD))[1];
        }

        // ---- QK^T: 16x64 scores per wave (exp2 domain) ----
        floatx4 c[4];
        #pragma unroll
        for (int nt = 0; nt < 4; ++nt) {
            bf16x8 b0 = *(const bf16x8*)&ks[nt * 16 + l15][quad * 8];
            bf16x8 b1 = *(const bf16x8*)&ks[nt * 16 + l15][32 + quad * 8];
            floatx4 z; z[0]=0.f; z[1]=0.f; z[2]=0.f; z[3]=0.f;
            z = __builtin_amdgcn_mfma_f32_16x16x32_bf16(aq[0], b0, z, 0, 0, 0);
            z = __builtin_amdgcn_mfma_f32_16x16x32_bf16(aq[1], b1, z, 0, 0, 0);
            c[nt] = z;
        }

        // ---- online softmax (max may include masked scores: scale-invariant) ----
        #pragma unroll
        for (int r = 0; r < 4; ++r) {
            float rm = fmaxf(fmaxf(c[0][r], c[1][r]), fmaxf(c[2][r], c[3][r]));
            rm = fmaxf(rm, __shfl_xor(rm, 1));
            rm = fmaxf(rm, __shfl_xor(rm, 2));
            rm = fmaxf(rm, __shfl_xor(rm, 4));
            rm = fmaxf(rm, __shfl_xor(rm, 8));
            float mnew  = fmaxf(mr[r], rm);
            float alpha = __builtin_amdgcn_exp2f(mr[r] - mnew);
            mr[r] = mnew;
            #pragma unroll
            for (int nt = 0; nt < 4; ++nt) o[nt][r] *= alpha;
            ol[r] *= alpha;
            #pragma unroll
            for (int nt = 0; nt < 4; ++nt) {
                float p = __builtin_amdgcn_exp2f(c[nt][r] - mnew);
                c[nt][r] = (mk[r][nt] == 1) ? 0.f : p;   // masked contribute 0 to o and l
            }
        }

        // ---- P (C-layout) -> LDS -> A-layout ----
        #pragma unroll
        for (int r = 0; r < 4; ++r) {
            #pragma unroll
            for (int nt = 0; nt < 4; ++nt) {
                ps[wave][quad * 4 + r][nt * 16 + l15] = (__bf16)c[nt][r];
            }
        }
        bf16x8 ap0 = *(const bf16x8*)&ps[wave][l15][quad * 8];
        bf16x8 ap1 = *(const bf16x8*)&ps[wave][l15][32 + quad * 8];

        // ---- PV + l-accumulation via ones-column MFMA ----
        #pragma unroll
        for (int nt = 0; nt < 4; ++nt) {
            bf16x8 bv0 = *(const bf16x8*)&vsT[nt * 16 + l15][quad * 8];
            bf16x8 bv1 = *(const bf16x8*)&vsT[nt * 16 + l15][32 + quad * 8];
            o[nt] = __builtin_amdgcn_mfma_f32_16x16x32_bf16(ap0, bv0, o[nt], 0, 0, 0);
            o[nt] = __builtin_amdgcn_mfma_f32_16x16x32_bf16(ap1, bv1, o[nt], 0, 0, 0);
        }
        ol = __builtin_amdgcn_mfma_f32_16x16x32_bf16(ap0, ones, ol, 0, 0, 0);
        ol = __builtin_amdgcn_mfma_f32_16x16x32_bf16(ap1, ones, ol, 0, 0, 0);
    }

    // ---- epilogue: every lane's ol[r] == l for its row ----
    #pragma unroll
    for (int r = 0; r < 4; ++r) {
        float inv = 1.0f / ol[r];
        float* op = O + base + (size_t)(q0 + quad * 4 + r) * DD + l15;
        #pragma unroll
        for (int nt = 0; nt < 4; ++nt) op[nt * 16] = o[nt][r] * inv;
    }
}

extern "C" void kernel_launch(void* const* d_in, const int* in_sizes, int n_in,
                              void* d_out, int out_size, void* d_ws, size_t ws_size,
                              hipStream_t stream) {
    (void)in_sizes; (void)n_in; (void)out_size; (void)d_ws; (void)ws_size;
    const float* q = (const float*)d_in[0];
    const float* k = (const float*)d_in[1];
    const float* v = (const float*)d_in[2];
    const int*   m = (const int*)d_in[3];
    float* out = (float*)d_out;
    dim3 grid(NB * NH * (SS / QT));   // 2048 blocks
    attn_kernel<<<grid, 256, 0, stream>>>(q, k, v, m, out);
}

// Round 3
// 401.968 us; speedup vs baseline: 1.0897x; 1.0166x over previous
//
#include <hip/hip_runtime.h>

#define NB 4
#define NH 16
#define SS 2048
#define DD 64
#define QT 64      // query rows per block (16 per wave)
#define KT 64      // keys per tile
#define DP 72      // padded LDS stride (bf16 elems)
#define PS 72      // P^T tile stride
#define QSCALE 0.18033688011112042f   // (1/8) * log2(e)  -> exp2 domain
#define MASK_BITS_BYTES ((size_t)NB * SS * (SS / 8))   // 2 MiB

typedef __bf16 bf16x8 __attribute__((ext_vector_type(8)));
typedef __bf16 bf16x4 __attribute__((ext_vector_type(4)));
typedef __bf16 bf16x2 __attribute__((ext_vector_type(2)));
typedef float  floatx4 __attribute__((ext_vector_type(4)));

static_assert(sizeof(bf16x8) == 16, "bf16x8 must be 16B");
static_assert(sizeof(bf16x4) == 8,  "bf16x4 must be 8B");

// ---- pre-pass: pack mask int32 [B,S,S] -> bits [B*S][S/64] (uint64) ----
__global__ __launch_bounds__(256)
void pack_mask_kernel(const int* __restrict__ M, unsigned long long* __restrict__ bits)
{
    int gw   = (blockIdx.x * 256 + threadIdx.x) >> 6;   // global wave id == word id
    int lane = threadIdx.x & 63;
    size_t row = (size_t)(gw >> 5);                     // S/64 = 32 words per row
    int word   = gw & 31;
    int mval = M[row * SS + (size_t)word * 64 + lane];
    unsigned long long b = __ballot(mval == 1);
    if (lane == 0) bits[gw] = b;
}

template<bool USE_BITS>
__global__ __launch_bounds__(256, 4)
void attn_kernel(const float* __restrict__ Q, const float* __restrict__ K,
                 const float* __restrict__ V, const int* __restrict__ M,
                 const uint2* __restrict__ MB, float* __restrict__ O)
{
    __shared__ __bf16 ks[KT][DP];        // K tile, [key][dim]
    __shared__ __bf16 vsT[DD][DP];       // V tile transposed, [dim][key]
    __shared__ __bf16 pst[4][16][PS];    // per-wave P^T as [qrow][key]

    const int t    = threadIdx.x;
    const int wave = t >> 6;
    const int lane = t & 63;
    const int l15  = lane & 15;
    const int quad = lane >> 4;

    const int bh    = blockIdx.x >> 5;
    const int qtile = blockIdx.x & 31;
    const int b     = bh >> 4;
    const int q0    = qtile * QT + wave * 16;

    const size_t base = (size_t)bh * SS * DD;
    const float* Qb = Q + base;
    const float* Kb = K + base;
    const float* Vb = V + base;

    // ---- persistent Q fragments (B-operand layout == A layout), exp2 domain ----
    bf16x8 aq[2];
    {
        const float* qp = Qb + (size_t)(q0 + l15) * DD + quad * 8;
        #pragma unroll
        for (int kc = 0; kc < 2; ++kc) {
            float4 f0 = *(const float4*)(qp + kc * 32);
            float4 f1 = *(const float4*)(qp + kc * 32 + 4);
            bf16x8 a;
            a[0] = (__bf16)(f0.x * QSCALE); a[1] = (__bf16)(f0.y * QSCALE);
            a[2] = (__bf16)(f0.z * QSCALE); a[3] = (__bf16)(f0.w * QSCALE);
            a[4] = (__bf16)(f1.x * QSCALE); a[5] = (__bf16)(f1.y * QSCALE);
            a[6] = (__bf16)(f1.z * QSCALE); a[7] = (__bf16)(f1.w * QSCALE);
            aq[kc] = a;
        }
    }

    // staging assignments
    const int skey = t >> 2;            // K: key 0..63
    const int sdc  = (t & 3) * 16;      // K: 16 dims
    const int vkp  = t & 31;            // V: key pair
    const int vdc  = (t >> 5) * 8;      // V: 8 dims

    const float* kpre = Kb + (size_t)skey * DD + sdc;
    const float* vpre = Vb + (size_t)(2 * vkp) * DD + vdc;

    // prologue prefetch tile 0
    float4 kr0, kr1, kr2, kr3, vr0, vr1, vr2, vr3;
    kr0 = ((const float4*)kpre)[0]; kr1 = ((const float4*)kpre)[1];
    kr2 = ((const float4*)kpre)[2]; kr3 = ((const float4*)kpre)[3];
    vr0 = ((const float4*)vpre)[0]; vr1 = ((const float4*)vpre)[1];
    vr2 = ((const float4*)(vpre + DD))[0]; vr3 = ((const float4*)(vpre + DD))[1];

    // mask pointers (row = q0 + l15)
    const uint2* mbrow = MB + ((size_t)b * SS + q0 + l15) * (SS / 64);
    const int*   mrow  = M + (size_t)b * SS * SS + (size_t)(q0 + l15) * SS + quad * 4;

    floatx4 o[4];       // O^T accum: o[mt][r] = O[row=l15][dim=mt*16+quad*4+r]
    floatx4 ol;         // l accum (all regs equal per lane)
    #pragma unroll
    for (int mt = 0; mt < 4; ++mt) { o[mt][0]=0.f; o[mt][1]=0.f; o[mt][2]=0.f; o[mt][3]=0.f; }
    ol[0]=0.f; ol[1]=0.f; ol[2]=0.f; ol[3]=0.f;
    float mr = -3.0e38f;

    bf16x8 ones;
    #pragma unroll
    for (int i = 0; i < 8; ++i) ones[i] = (__bf16)1.0f;

    for (int tt = 0; tt < SS / KT; ++tt) {
        const int j0 = tt * KT;
        __syncthreads();   // previous tile's LDS consumers done

        // ---- regs -> LDS (K natural, V transposed) ----
        {
            bf16x8 w0, w1;
            w0[0]=(__bf16)kr0.x; w0[1]=(__bf16)kr0.y; w0[2]=(__bf16)kr0.z; w0[3]=(__bf16)kr0.w;
            w0[4]=(__bf16)kr1.x; w0[5]=(__bf16)kr1.y; w0[6]=(__bf16)kr1.z; w0[7]=(__bf16)kr1.w;
            w1[0]=(__bf16)kr2.x; w1[1]=(__bf16)kr2.y; w1[2]=(__bf16)kr2.z; w1[3]=(__bf16)kr2.w;
            w1[4]=(__bf16)kr3.x; w1[5]=(__bf16)kr3.y; w1[6]=(__bf16)kr3.z; w1[7]=(__bf16)kr3.w;
            *(bf16x8*)&ks[skey][sdc]     = w0;
            *(bf16x8*)&ks[skey][sdc + 8] = w1;
        }
        {
            float av[8] = {vr0.x,vr0.y,vr0.z,vr0.w,vr1.x,vr1.y,vr1.z,vr1.w};
            float bv[8] = {vr2.x,vr2.y,vr2.z,vr2.w,vr3.x,vr3.y,vr3.z,vr3.w};
            #pragma unroll
            for (int i = 0; i < 8; ++i) {
                bf16x2 pr; pr[0] = (__bf16)av[i]; pr[1] = (__bf16)bv[i];
                *(bf16x2*)&vsT[vdc + i][2 * vkp] = pr;
            }
        }
        __syncthreads();   // staged tile visible

        // ---- mask fetch for current tile ----
        uint2 mw;
        int   mi[4][4];
        if (USE_BITS) {
            mw = mbrow[tt];                      // 64 bits = whole key tile for row l15
        } else {
            #pragma unroll
            for (int mt = 0; mt < 4; ++mt) {
                int4 m4 = *(const int4*)(mrow + j0 + mt * 16);
                mi[mt][0] = m4.x; mi[mt][1] = m4.y; mi[mt][2] = m4.z; mi[mt][3] = m4.w;
            }
        }

        // ---- prefetch next K/V tile ----
        {
            int jn = (j0 + KT) & (SS - 1);
            const float* kn = kpre + (size_t)jn * DD;
            kr0 = ((const float4*)kn)[0]; kr1 = ((const float4*)kn)[1];
            kr2 = ((const float4*)kn)[2]; kr3 = ((const float4*)kn)[3];
            const float* vn = vpre + (size_t)jn * DD;
            vr0 = ((const float4*)vn)[0]; vr1 = ((const float4*)vn)[1];
            vr2 = ((const float4*)(vn + DD))[0]; vr3 = ((const float4*)(vn + DD))[1];
        }

        // ---- S^T = K·Q^T : c[mt][r] = score(row=l15, key=mt*16+quad*4+r) ----
        floatx4 c[4];
        #pragma unroll
        for (int mt = 0; mt < 4; ++mt) {
            bf16x8 a0 = *(const bf16x8*)&ks[mt * 16 + l15][quad * 8];
            bf16x8 a1 = *(const bf16x8*)&ks[mt * 16 + l15][32 + quad * 8];
            floatx4 z; z[0]=0.f; z[1]=0.f; z[2]=0.f; z[3]=0.f;
            z = __builtin_amdgcn_mfma_f32_16x16x32_bf16(a0, aq[0], z, 0, 0, 0);
            z = __builtin_amdgcn_mfma_f32_16x16x32_bf16(a1, aq[1], z, 0, 0, 0);
            c[mt] = z;
        }

        // ---- online softmax (single row per lane; reduce across quads) ----
        float rm = c[0][0];
        #pragma unroll
        for (int mt = 0; mt < 4; ++mt) {
            #pragma unroll
            for (int r = 0; r < 4; ++r) rm = fmaxf(rm, c[mt][r]);
        }
        rm = fmaxf(rm, __shfl_xor(rm, 16));
        rm = fmaxf(rm, __shfl_xor(rm, 32));
        float mnew  = fmaxf(mr, rm);
        float alpha = __builtin_amdgcn_exp2f(mr - mnew);
        mr = mnew;
        #pragma unroll
        for (int mt = 0; mt < 4; ++mt) {
            o[mt][0] *= alpha; o[mt][1] *= alpha; o[mt][2] *= alpha; o[mt][3] *= alpha;
        }
        ol[0] *= alpha; ol[1] *= alpha; ol[2] *= alpha; ol[3] *= alpha;

        unsigned un[4];
        if (USE_BITS) {
            un[0] = mw.x >> (quad * 4);
            un[1] = mw.x >> (quad * 4 + 16);
            un[2] = mw.y >> (quad * 4);
            un[3] = mw.y >> (quad * 4 + 16);
        }
        #pragma unroll
        for (int mt = 0; mt < 4; ++mt) {
            #pragma unroll
            for (int r = 0; r < 4; ++r) {
                float p = __builtin_amdgcn_exp2f(c[mt][r] - mnew);
                bool masked = USE_BITS ? ((un[mt] & (1u << r)) != 0) : (mi[mt][r] == 1);
                c[mt][r] = masked ? 0.f : p;
            }
        }

        // ---- P^T -> LDS [row][key], 4x b64 writes ----
        #pragma unroll
        for (int mt = 0; mt < 4; ++mt) {
            bf16x4 pk;
            pk[0] = (__bf16)c[mt][0]; pk[1] = (__bf16)c[mt][1];
            pk[2] = (__bf16)c[mt][2]; pk[3] = (__bf16)c[mt][3];
            *(bf16x4*)&pst[wave][l15][mt * 16 + quad * 4] = pk;
        }
        // same-wave write->read, no barrier needed
        bf16x8 bp0 = *(const bf16x8*)&pst[wave][l15][quad * 8];
        bf16x8 bp1 = *(const bf16x8*)&pst[wave][l15][32 + quad * 8];

        // ---- O^T += V^T · P^T ----
        #pragma unroll
        for (int mt = 0; mt < 4; ++mt) {
            bf16x8 av0 = *(const bf16x8*)&vsT[mt * 16 + l15][quad * 8];
            bf16x8 av1 = *(const bf16x8*)&vsT[mt * 16 + l15][32 + quad * 8];
            o[mt] = __builtin_amdgcn_mfma_f32_16x16x32_bf16(av0, bp0, o[mt], 0, 0, 0);
            o[mt] = __builtin_amdgcn_mfma_f32_16x16x32_bf16(av1, bp1, o[mt], 0, 0, 0);
        }
        ol = __builtin_amdgcn_mfma_f32_16x16x32_bf16(ones, bp0, ol, 0, 0, 0);
        ol = __builtin_amdgcn_mfma_f32_16x16x32_bf16(ones, bp1, ol, 0, 0, 0);
    }

    // ---- epilogue: O^T C-layout -> coalesced float4 stores ----
    float inv = 1.0f / ol[0];
    float* op = O + base + (size_t)(q0 + l15) * DD + quad * 4;
    #pragma unroll
    for (int mt = 0; mt < 4; ++mt) {
        float4 st;
        st.x = o[mt][0] * inv; st.y = o[mt][1] * inv;
        st.z = o[mt][2] * inv; st.w = o[mt][3] * inv;
        *(float4*)(op + mt * 16) = st;
    }
}

extern "C" void kernel_launch(void* const* d_in, const int* in_sizes, int n_in,
                              void* d_out, int out_size, void* d_ws, size_t ws_size,
                              hipStream_t stream) {
    (void)in_sizes; (void)n_in; (void)out_size;
    const float* q = (const float*)d_in[0];
    const float* k = (const float*)d_in[1];
    const float* v = (const float*)d_in[2];
    const int*   m = (const int*)d_in[3];
    float* out = (float*)d_out;
    dim3 grid(NB * NH * (SS / QT));   // 2048 blocks

    if (ws_size >= MASK_BITS_BYTES) {
        unsigned long long* bits = (unsigned long long*)d_ws;
        // 262144 words, 4 words per 256-thread block
        pack_mask_kernel<<<dim3(NB * SS * (SS / 64) / 4), 256, 0, stream>>>(m, bits);
        attn_kernel<true><<<grid, 256, 0, stream>>>(q, k, v, m, (const uint2*)bits, out);
    } else {
        attn_kernel<false><<<grid, 256, 0, stream>>>(q, k, v, m, (const uint2*)nullptr, out);
    }
}

// Round 4
// 320.827 us; speedup vs baseline: 1.3653x; 1.2529x over previous
//
#include <hip/hip_runtime.h>

#define NB 4
#define NH 16
#define SS 2048
#define DD 64
#define QT 128     // query rows per block (32 per wave)
#define KT 32      // keys per tile
#define KSP 72     // ks stride (bf16): 144B rows, 16B aligned
#define VSP 40     // vsT stride (bf16): 80B rows, 16B aligned
#define QSCALE 0.18033688011112042f   // (1/8) * log2(e)  -> exp2 domain
#define MASK_BITS_BYTES ((size_t)NB * SS * (SS / 8))   // 2 MiB

typedef __bf16 bf16x8  __attribute__((ext_vector_type(8)));
typedef __bf16 bf16x2  __attribute__((ext_vector_type(2)));
typedef float  floatx16 __attribute__((ext_vector_type(16)));

static_assert(sizeof(bf16x8) == 16, "bf16x8 must be 16B");

__device__ __forceinline__ int pack2(float a, float b) {
    bf16x2 v; v[0] = (__bf16)a; v[1] = (__bf16)b;
    return __builtin_bit_cast(int, v);
}

// ---- pre-pass: pack mask int32 [B,S,S] -> bits [B*S][S/64] (uint64) ----
__global__ __launch_bounds__(256)
void pack_mask_kernel(const int* __restrict__ M, unsigned long long* __restrict__ bits)
{
    int gw   = (blockIdx.x * 256 + threadIdx.x) >> 6;
    int lane = threadIdx.x & 63;
    size_t row = (size_t)(gw >> 5);
    int word   = gw & 31;
    int mval = M[row * SS + (size_t)word * 64 + lane];
    unsigned long long b = __ballot(mval == 1);
    if (lane == 0) bits[gw] = b;
}

template<bool USE_BITS>
__global__ __launch_bounds__(256, 4)
void attn_kernel(const float* __restrict__ Q, const float* __restrict__ K,
                 const float* __restrict__ V, const int* __restrict__ M,
                 const unsigned* __restrict__ MB, float* __restrict__ O)
{
    __shared__ __bf16 ks[KT][KSP];    // K tile, [key][dim]
    __shared__ __bf16 vsT[DD][VSP];   // V tile transposed, [dim][key]

    const int t    = threadIdx.x;
    const int wave = t >> 6;
    const int lane = t & 63;
    const int l31  = lane & 31;
    const int h8   = lane >> 5;

    const int bh    = blockIdx.x >> 4;    // 16 q-tiles per (b,h)
    const int qtile = blockIdx.x & 15;
    const int b     = bh >> 4;
    const int q0    = qtile * QT + wave * 32;

    const size_t base = (size_t)bh * SS * DD;
    const float* Qb = Q + base;
    const float* Kb = K + base;
    const float* Vb = V + base;

    // ---- persistent Q B-fragments: B[k=16s+8*h8+j][n=q=l31], exp2 domain ----
    bf16x8 aq[4];
    {
        const float* qp = Qb + (size_t)(q0 + l31) * DD + 8 * h8;
        #pragma unroll
        for (int s = 0; s < 4; ++s) {
            float4 f0 = *(const float4*)(qp + 16 * s);
            float4 f1 = *(const float4*)(qp + 16 * s + 4);
            bf16x8 a;
            a[0] = (__bf16)(f0.x * QSCALE); a[1] = (__bf16)(f0.y * QSCALE);
            a[2] = (__bf16)(f0.z * QSCALE); a[3] = (__bf16)(f0.w * QSCALE);
            a[4] = (__bf16)(f1.x * QSCALE); a[5] = (__bf16)(f1.y * QSCALE);
            a[6] = (__bf16)(f1.z * QSCALE); a[7] = (__bf16)(f1.w * QSCALE);
            aq[s] = a;
        }
    }

    // staging assignments (256 threads)
    const int skey = t >> 3;            // K: key 0..31
    const int sdc  = (t & 7) * 8;       // K: 8 dims
    const int vkp  = t & 15;            // V: key pair (2vkp, 2vkp+1)
    const int vdc  = (t >> 4) * 4;      // V: 4 dims

    const float* kpre = Kb + (size_t)skey * DD + sdc;
    const float* vpre = Vb + (size_t)(2 * vkp) * DD + vdc;

    // prologue: prefetch tile 0
    float4 ka0 = ((const float4*)kpre)[0];
    float4 ka1 = ((const float4*)(kpre + 4))[0];
    float4 va0 = *(const float4*)vpre;
    float4 va1 = *(const float4*)(vpre + DD);

    // mask pointers for row (q0 + l31)
    const unsigned* mbrow = MB + ((size_t)b * SS + q0 + l31) * (SS / 32);
    const int*      mrow  = M + (size_t)b * SS * SS + (size_t)(q0 + l31) * SS + 4 * h8;

    floatx16 o0, o1;
    #pragma unroll
    for (int i = 0; i < 16; ++i) { o0[i] = 0.f; o1[i] = 0.f; }
    float ls = 0.f;
    float mr = -3.0e38f;

    for (int tt = 0; tt < SS / KT; ++tt) {
        const int j0 = tt * KT;
        __syncthreads();   // previous tile's LDS consumers done

        // ---- regs -> LDS ----
        {
            bf16x8 kw;
            kw[0]=(__bf16)ka0.x; kw[1]=(__bf16)ka0.y; kw[2]=(__bf16)ka0.z; kw[3]=(__bf16)ka0.w;
            kw[4]=(__bf16)ka1.x; kw[5]=(__bf16)ka1.y; kw[6]=(__bf16)ka1.z; kw[7]=(__bf16)ka1.w;
            *(bf16x8*)&ks[skey][sdc] = kw;
            float av[4] = {va0.x, va0.y, va0.z, va0.w};
            float bv[4] = {va1.x, va1.y, va1.z, va1.w};
            #pragma unroll
            for (int i = 0; i < 4; ++i) {
                bf16x2 pr; pr[0] = (__bf16)av[i]; pr[1] = (__bf16)bv[i];
                *(bf16x2*)&vsT[vdc + i][2 * vkp] = pr;
            }
        }
        __syncthreads();   // staged tile visible

        // ---- mask fetch for current tile ----
        unsigned mw = 0;
        int mia[4][4];
        if (USE_BITS) {
            mw = mbrow[tt];
        } else {
            #pragma unroll
            for (int s = 0; s < 4; ++s) {
                int4 m4 = *(const int4*)(mrow + j0 + 8 * s);
                mia[s][0] = m4.x; mia[s][1] = m4.y; mia[s][2] = m4.z; mia[s][3] = m4.w;
            }
        }

        // ---- prefetch next K/V tile ----
        {
            int jn = (j0 + KT) & (SS - 1);
            const float* kn = kpre + (size_t)jn * DD;
            ka0 = ((const float4*)kn)[0];
            ka1 = ((const float4*)(kn + 4))[0];
            const float* vn = vpre + (size_t)jn * DD;
            va0 = *(const float4*)vn;
            va1 = *(const float4*)(vn + DD);
        }

        // ---- S^T = K·Q^T : C[m=key][n=q=l31], key = (i&3)+8*(i>>2)+4*h8 ----
        floatx16 c;
        #pragma unroll
        for (int i = 0; i < 16; ++i) c[i] = 0.f;
        #pragma unroll
        for (int s = 0; s < 4; ++s) {
            bf16x8 a = *(const bf16x8*)&ks[l31][16 * s + 8 * h8];
            c = __builtin_amdgcn_mfma_f32_32x32x16_bf16(a, aq[s], c, 0, 0, 0);
        }

        // ---- online softmax (one q-row per lane-column) ----
        float rm = c[0];
        #pragma unroll
        for (int i = 1; i < 16; ++i) rm = fmaxf(rm, c[i]);
        rm = fmaxf(rm, __shfl_xor(rm, 32));
        float mnew  = fmaxf(mr, rm);
        float alpha = __builtin_amdgcn_exp2f(mr - mnew);
        mr = mnew;
        o0 *= alpha;
        o1 *= alpha;
        ls *= alpha;

        unsigned un = mw >> (4 * h8);
        float psum = 0.f;
        #pragma unroll
        for (int i = 0; i < 16; ++i) {
            float p = __builtin_amdgcn_exp2f(c[i] - mnew);
            bool masked = USE_BITS ? (((un >> ((i & 3) + 8 * (i >> 2))) & 1u) != 0)
                                   : (mia[i >> 2][i & 3] == 1);
            p = masked ? 0.f : p;
            c[i] = p;
            psum += p;
        }
        psum += __shfl_xor(psum, 32);
        ls += psum;

        // ---- pack P^T to bf16 pairs: pk[g] = (c[2g+1], c[2g]) ----
        int pk[8];
        #pragma unroll
        for (int g = 0; g < 8; ++g) pk[g] = pack2(c[2 * g], c[2 * g + 1]);

        // ---- PV: O^T += V^T · P^T, two 16-key steps ----
        #pragma unroll
        for (int s2 = 0; s2 < 2; ++s2) {
            // own group (2*s2 + h8), partner's group via xor-32 shuffle
            int g0 = h8 ? pk[4 * s2 + 2] : pk[4 * s2];
            int g1 = h8 ? pk[4 * s2 + 3] : pk[4 * s2 + 1];
            int s0 = h8 ? pk[4 * s2]     : pk[4 * s2 + 2];
            int s1 = h8 ? pk[4 * s2 + 1] : pk[4 * s2 + 3];
            int r0 = __shfl_xor(s0, 32);
            int r1 = __shfl_xor(s1, 32);
            int4 fw;
            fw.x = h8 ? r0 : g0;
            fw.y = h8 ? r1 : g1;
            fw.z = h8 ? g0 : r0;
            fw.w = h8 ? g1 : r1;
            bf16x8 bp = __builtin_bit_cast(bf16x8, fw);
            bf16x8 av0 = *(const bf16x8*)&vsT[l31][16 * s2 + 8 * h8];
            bf16x8 av1 = *(const bf16x8*)&vsT[32 + l31][16 * s2 + 8 * h8];
            o0 = __builtin_amdgcn_mfma_f32_32x32x16_bf16(av0, bp, o0, 0, 0, 0);
            o1 = __builtin_amdgcn_mfma_f32_32x32x16_bf16(av1, bp, o1, 0, 0, 0);
        }
    }

    // ---- epilogue: O^T C-layout -> float4 stores; all 32 o-regs are row l31 ----
    float inv = 1.0f / ls;
    float* op = O + base + (size_t)(q0 + l31) * DD;
    #pragma unroll
    for (int s = 0; s < 4; ++s) {
        float4 st0, st1;
        st0.x = o0[4*s+0] * inv; st0.y = o0[4*s+1] * inv;
        st0.z = o0[4*s+2] * inv; st0.w = o0[4*s+3] * inv;
        st1.x = o1[4*s+0] * inv; st1.y = o1[4*s+1] * inv;
        st1.z = o1[4*s+2] * inv; st1.w = o1[4*s+3] * inv;
        *(float4*)(op + 8 * s + 4 * h8)      = st0;
        *(float4*)(op + 32 + 8 * s + 4 * h8) = st1;
    }
}

extern "C" void kernel_launch(void* const* d_in, const int* in_sizes, int n_in,
                              void* d_out, int out_size, void* d_ws, size_t ws_size,
                              hipStream_t stream) {
    (void)in_sizes; (void)n_in; (void)out_size;
    const float* q = (const float*)d_in[0];
    const float* k = (const float*)d_in[1];
    const float* v = (const float*)d_in[2];
    const int*   m = (const int*)d_in[3];
    float* out = (float*)d_out;
    dim3 grid(NB * NH * (SS / QT));   // 1024 blocks = 4 per CU

    if (ws_size >= MASK_BITS_BYTES) {
        unsigned long long* bits = (unsigned long long*)d_ws;
        pack_mask_kernel<<<dim3(NB * SS * (SS / 64) / 4), 256, 0, stream>>>(m, bits);
        attn_kernel<true><<<grid, 256, 0, stream>>>(q, k, v, m, (const unsigned*)bits, out);
    } else {
        attn_kernel<false><<<grid, 256, 0, stream>>>(q, k, v, m, (const unsigned*)nullptr, out);
    }
}